// Round 1
// baseline (601.140 us; speedup 1.0000x reference)
//
#include <hip/hip_runtime.h>
#include <cstdint>
#include <cmath>

// Problem dims
#define B_   128
#define N_   196
#define D_   768
#define H_   3072
#define R_   384
#define TOK  (B_*N_)      // 25088

typedef int i32x4 __attribute__((ext_vector_type(4)));

// ---------------- workspace layout (bytes) ----------------
// peak ~118 MiB; A6 overlays A0T (dead after attn) by design.
#define OFF_AMAX   0L
#define OFF_QVEC   1024L                 // 4 x 768 fp32 quantized vectors
#define OFF_WQA    (16L*1024)            // attn weight int8 padded [256][256]
#define OFF_W1VT   (128L*1024)           // [384][768]
#define OFF_W1U    (512L*1024)           // [3072][384]
#define OFF_W2VT   (2L*1024*1024)        // [384][3072]
#define OFF_W2U    (3328L*1024)          // [768][384]
#define OFF_X1Q    (4L*1024*1024)        // int8 [25088][768]
#define OFF_A4     (24L*1024*1024)       // int8 [25088][384]
#define OFF_A7     (34L*1024*1024)       // int8 [25088][384]
#define OFF_A0T    (44L*1024*1024)       // int8 [128][768][256] (dead after attn)
#define OFF_A2     (68L*1024*1024)       // int8 [25088][768]    (dead after fc1_vt)
#define OFF_A6     (44L*1024*1024)       // int8 [25088][3072]   (overlays A0T+A2)

__device__ __forceinline__ float rclipf(float v) {
  // clip(round_half_even(v), -128, 127) ; matches jnp.clip(jnp.round(x),-n,n-1)
  return fminf(fmaxf(rintf(v), -128.f), 127.f);
}

// ---------------- absmax over 9 weight tensors ----------------
__global__ void absmax_k(const float* p0, const float* p1, const float* p2,
                         const float* p3, const float* p4, const float* p5,
                         const float* p6, const float* p7, const float* p8,
                         float* amax) {
  int tsel = blockIdx.y;
  const float* src; int n;
  switch (tsel) {
    case 0: src = p0; n = 768;     break;  // norm1_a
    case 1: src = p1; n = N_*N_;   break;  // attn_w
    case 2: src = p2; n = 768;     break;  // gamma1
    case 3: src = p3; n = 768;     break;  // norm2_a
    case 4: src = p4; n = R_*D_;   break;  // fc1_vt_w
    case 5: src = p5; n = H_*R_;   break;  // fc1_u_w
    case 6: src = p6; n = R_*H_;   break;  // fc2_vt_w
    case 7: src = p7; n = D_*R_;   break;  // fc2_u_w
    default: src = p8; n = 768;    break;  // gamma2
  }
  float m = 0.f;
  for (int i = blockIdx.x*blockDim.x + threadIdx.x; i < n; i += gridDim.x*blockDim.x)
    m = fmaxf(m, fabsf(src[i]));
  #pragma unroll
  for (int off = 32; off > 0; off >>= 1)
    m = fmaxf(m, __shfl_down(m, off));
  if ((threadIdx.x & 63) == 0)
    atomicMax((int*)(amax + tsel), __float_as_int(m));  // non-negative floats: int order == float order
}

// ---------------- quantize the 4 affine vectors (forward value, fp32) ----------------
__global__ void quant_vec_k(const float* n1a, const float* g1, const float* n2a,
                            const float* g2, const float* amax, float* dst) {
  int tsel = blockIdx.x, i = threadIdx.x;  // 768 threads
  const float* src; int ai;
  switch (tsel) {
    case 0: src = n1a; ai = 0; break;
    case 1: src = g1;  ai = 2; break;
    case 2: src = n2a; ai = 3; break;
    default: src = g2; ai = 8; break;
  }
  float s = amax[ai] / 127.f + 1e-8f;
  dst[tsel*768 + i] = s * rclipf(src[i] / s);
}

// ---------------- quantize a matmul weight to int8 ----------------
__global__ void quant_w_k(const float* w, int8_t* dst, int n, const float* amaxp) {
  int i = blockIdx.x*blockDim.x + threadIdx.x;
  if (i >= n) return;
  float s = *amaxp / 127.f + 1e-8f;
  dst[i] = (int8_t)(int)rclipf(w[i] / s);
}

// attn weight: quantize + zero-pad into [256][256]
__global__ void quant_attn_k(const float* w, int8_t* dst, const float* amaxp) {
  int i = blockIdx.x*blockDim.x + threadIdx.x;  // 65536
  int m = i >> 8, n = i & 255;
  float s = *amaxp / 127.f + 1e-8f;
  int8_t q = 0;
  if (m < N_ && n < N_) q = (int8_t)(int)rclipf(w[m*N_ + n] / s);
  dst[i] = q;
}

// ---------------- stage A: norm1 affine + act-quant, transposed to A0T[b][d][n256] ----------------
__global__ void stageA_k(const float* __restrict__ x, const float* __restrict__ qn1a,
                         const float* __restrict__ n1b, const float* __restrict__ actS,
                         int8_t* __restrict__ A0T) {
  __shared__ int8_t ldsT[64*68];   // [d][n] tile, pad 68 keeps u32 align + conflict-free
  const int dt = blockIdx.x;   // 0..11 (d tile of 64)
  const int nt = blockIdx.y;   // 0..3  (n tile of 64, n padded to 256)
  const int b  = blockIdx.z;
  const float s0 = actS[0];
  const int d0 = dt*64, n0 = nt*64;
  const int tid = threadIdx.x;
  const int dc = tid & 63, nr4 = tid >> 6;
  const float qa = qn1a[d0 + dc];
  const float bb = n1b[d0 + dc];
  #pragma unroll 4
  for (int it = 0; it < 16; ++it) {
    int nl = nr4 + it*4;
    int n = n0 + nl;
    int8_t q = 0;
    if (n < N_) {
      float v = x[((long)b*N_ + n)*D_ + d0 + dc] * qa + bb;
      q = (int8_t)(int)rclipf(v / s0);
    }
    ldsT[dc*68 + nl] = q;
  }
  __syncthreads();
  const int k = tid & 15, dr = tid >> 4;
  #pragma unroll
  for (int it = 0; it < 4; ++it) {
    int d = dr + it*16;
    uint32_t v = *(const uint32_t*)(&ldsT[d*68 + k*4]);
    *(uint32_t*)(&A0T[(long)b*(D_*256) + (long)(d0+d)*256 + n0 + k*4]) = v;
  }
}

// ---------------- generic i8 GEMM: Out[i,j] = sum_k A[i,k]*W[j,k] ----------------
// BM=BN=128, BK=64; 4 waves, each 64x64 via 4x4 of mfma_i32_16x16x64_i8.
// Epilogues: 0=attn(+gamma1+res+norm2+act3), 1=plain quant, 2=quant+GELU+quant, 3=final.
struct GemmParams {
  const int8_t* A;
  const int8_t* W;
  int K, MT, NT;
  long batchStrideA;
  const float* actS;
  const float* amax;
  int amaxIdx, sInIdx, sOutIdx, sOut2Idx;
  const float* bias;
  int8_t* out8;
  int ldOut;
  // attn epilogue
  const float* xorg;
  const float* qg1;
  const float* qn2a;
  const float* n2b;
  int8_t* X1q;
  int8_t* A2;
  // final epilogue
  const float* qg2;
  const int8_t* X1qIn;
  float* outF;
};

template<int EPI>
__launch_bounds__(256, 2)
__global__ void gemm_i8(GemmParams p) {
  __shared__ __align__(16) int8_t lsA[2][128][80];   // pad 80B row: 2-way LDS conflicts (free)
  __shared__ __align__(16) int8_t lsB[2][128][80];
  const int K  = p.K;
  const int bx = blockIdx.x;
  const int mt = bx % p.MT;
  const int nt = bx / p.MT;
  const int t    = threadIdx.x;
  const int wid  = t >> 6;
  const int lane = t & 63;
  const int wm = wid & 1, wn = wid >> 1;
  const int quad = lane >> 4, l15 = lane & 15;

  const int8_t* Abase = p.A + (long)blockIdx.y * p.batchStrideA + (long)mt*128*K;
  const int8_t* Wbase = p.W + (long)nt*128*K;

  const int ar = t >> 2;         // 0..63 (row), +64 for second half
  const int ac = (t & 3) * 16;   // 16B chunk within the 64B k-slice

  i32x4 ra0, ra1, rb0, rb1;
  auto gload = [&](int k0) {
    ra0 = *(const i32x4*)(Abase + (long)ar*K       + k0 + ac);
    ra1 = *(const i32x4*)(Abase + (long)(ar+64)*K  + k0 + ac);
    rb0 = *(const i32x4*)(Wbase + (long)ar*K       + k0 + ac);
    rb1 = *(const i32x4*)(Wbase + (long)(ar+64)*K  + k0 + ac);
  };
  auto lstore = [&](int buf) {
    *(i32x4*)(&lsA[buf][ar][ac])    = ra0;
    *(i32x4*)(&lsA[buf][ar+64][ac]) = ra1;
    *(i32x4*)(&lsB[buf][ar][ac])    = rb0;
    *(i32x4*)(&lsB[buf][ar+64][ac]) = rb1;
  };

  const i32x4 zero = {0, 0, 0, 0};
  i32x4 acc[4][4];
  #pragma unroll
  for (int i = 0; i < 4; ++i)
    #pragma unroll
    for (int j = 0; j < 4; ++j) acc[i][j] = zero;

  gload(0); lstore(0); __syncthreads();
  const int KT = K >> 6;
  for (int kt = 0; kt < KT; ++kt) {
    const int cur = kt & 1;
    if (kt + 1 < KT) gload((kt + 1) << 6);   // async-ish: vmcnt waited at lstore
    i32x4 af[4], bf[4];
    #pragma unroll
    for (int i = 0; i < 4; ++i)
      af[i] = *(const i32x4*)(&lsA[cur][wm*64 + i*16 + l15][quad*16]);
    #pragma unroll
    for (int j = 0; j < 4; ++j)
      bf[j] = *(const i32x4*)(&lsB[cur][wn*64 + j*16 + l15][quad*16]);
    #pragma unroll
    for (int i = 0; i < 4; ++i)
      #pragma unroll
      for (int j = 0; j < 4; ++j)
        acc[i][j] = __builtin_amdgcn_mfma_i32_16x16x64_i8(af[i], bf[j], acc[i][j], 0, 0, 0);
    if (kt + 1 < KT) { lstore(cur ^ 1); __syncthreads(); }
  }

  // ---- epilogue ---- C/D layout (16x16, m89-verified): col=lane&15, row=quad*4+reg
  const float sW  = p.amax[p.amaxIdx] / 127.f + 1e-8f;
  const float sAB = p.actS[p.sInIdx] * sW;
  const int i0 = mt*128 + wm*64;
  const int j0 = nt*128 + wn*64;

  #pragma unroll
  for (int ii = 0; ii < 4; ++ii) {
    #pragma unroll
    for (int jj = 0; jj < 4; ++jj) {
      const int i = i0 + ii*16 + quad*4;   // GEMM row
      const int j = j0 + jj*16 + l15;      // GEMM col
      if constexpr (EPI == 0) {
        // i = d (0..767), j = m patch (guard <196), batch = blockIdx.y
        if (j < N_) {
          const float s1v = p.actS[1], s8v = p.actS[8], s2v = p.actS[2];
          const float bj = p.bias[j];
          const long tok = (long)blockIdx.y * N_ + j;
          const float4 xo = *(const float4*)(p.xorg + tok*D_ + i);
          uint32_t pk8 = 0, pk2 = 0;
          #pragma unroll
          for (int r = 0; r < 4; ++r) {
            float v  = sAB * (float)acc[ii][jj][r] + bj;          // attn out + bias
            float q1 = rclipf(v / s1v);                           // act2
            float h  = s1v * q1 * p.qg1[i+r];                     // gamma_1
            float rs = h + ((const float*)&xo)[r];                // + org
            float q8 = rclipf(rs / s8v);                          // add_1 (res 8-bit)
            float x1 = s8v * q8;
            float t2 = x1 * p.qn2a[i+r] + p.n2b[i+r];             // norm2
            float q2 = rclipf(t2 / s2v);                          // act3
            pk8 |= ((uint32_t)(uint8_t)(int8_t)(int)q8) << (8*r);
            pk2 |= ((uint32_t)(uint8_t)(int8_t)(int)q2) << (8*r);
          }
          *(uint32_t*)(p.X1q + tok*D_ + i) = pk8;
          *(uint32_t*)(p.A2  + tok*D_ + i) = pk2;
        }
      } else if constexpr (EPI == 1) {
        const float sO = p.actS[p.sOutIdx];
        const float bj = p.bias[j];
        #pragma unroll
        for (int r = 0; r < 4; ++r) {
          float v = sAB * (float)acc[ii][jj][r] + bj;
          p.out8[(long)(i+r)*p.ldOut + j] = (int8_t)(int)rclipf(v / sO);
        }
      } else if constexpr (EPI == 2) {
        const float s5v = p.actS[p.sOutIdx], s6v = p.actS[p.sOut2Idx];
        const float bj = p.bias[j];
        #pragma unroll
        for (int r = 0; r < 4; ++r) {
          float v  = sAB * (float)acc[ii][jj][r] + bj;
          float v5 = s5v * rclipf(v / s5v);                       // act2 (return_fp)
          float g  = 0.5f * v5 * (1.f + erff(v5 * 0.70710678118654752f)); // exact GELU
          p.out8[(long)(i+r)*p.ldOut + j] = (int8_t)(int)rclipf(g / s6v); // act3
        }
      } else {
        const float s3v = p.actS[3], s8v = p.actS[8], s9v = p.actS[9];
        const float bj = p.bias[j];
        const float g2 = p.qg2[j];
        #pragma unroll
        for (int r = 0; r < 4; ++r) {
          long idx = (long)(i+r)*D_ + j;
          float v  = sAB * (float)acc[ii][jj][r] + bj;
          float q3 = rclipf(v / s3v);                             // block act4
          float h  = s3v * q3 * g2;                               // gamma_2
          float o  = h + s8v * (float)p.X1qIn[idx];               // + org (x1)
          p.outF[idx] = s9v * rclipf(o / s9v);                    // add_2
        }
      }
    }
  }
}

// ---------------- host launch ----------------
extern "C" void kernel_launch(void* const* d_in, const int* in_sizes, int n_in,
                              void* d_out, int out_size, void* d_ws, size_t ws_size,
                              hipStream_t stream) {
  (void)in_sizes; (void)n_in; (void)out_size; (void)ws_size;
  const float* x    = (const float*)d_in[0];
  const float* n1a  = (const float*)d_in[1];
  const float* n1b  = (const float*)d_in[2];
  const float* attw = (const float*)d_in[3];
  const float* attb = (const float*)d_in[4];
  const float* g1   = (const float*)d_in[5];
  const float* n2a  = (const float*)d_in[6];
  const float* n2b  = (const float*)d_in[7];
  const float* w1vt = (const float*)d_in[8];
  const float* b1vt = (const float*)d_in[9];
  const float* w1u  = (const float*)d_in[10];
  const float* b1u  = (const float*)d_in[11];
  const float* w2vt = (const float*)d_in[12];
  const float* b2vt = (const float*)d_in[13];
  const float* w2u  = (const float*)d_in[14];
  const float* b2u  = (const float*)d_in[15];
  const float* g2   = (const float*)d_in[16];
  const float* actS = (const float*)d_in[17];
  float* out = (float*)d_out;
  char* ws = (char*)d_ws;

  float*  amax = (float*)(ws + OFF_AMAX);
  float*  qvec = (float*)(ws + OFF_QVEC);
  int8_t* WQA  = (int8_t*)(ws + OFF_WQA);
  int8_t* W1VT = (int8_t*)(ws + OFF_W1VT);
  int8_t* W1U  = (int8_t*)(ws + OFF_W1U);
  int8_t* W2VT = (int8_t*)(ws + OFF_W2VT);
  int8_t* W2U  = (int8_t*)(ws + OFF_W2U);
  int8_t* X1Q  = (int8_t*)(ws + OFF_X1Q);
  int8_t* A4   = (int8_t*)(ws + OFF_A4);
  int8_t* A7   = (int8_t*)(ws + OFF_A7);
  int8_t* A0T  = (int8_t*)(ws + OFF_A0T);
  int8_t* A2   = (int8_t*)(ws + OFF_A2);
  int8_t* A6   = (int8_t*)(ws + OFF_A6);

  hipMemsetAsync(amax, 0, 64, stream);
  absmax_k<<<dim3(32, 9), 256, 0, stream>>>(n1a, attw, g1, n2a, w1vt, w1u, w2vt, w2u, g2, amax);
  quant_vec_k<<<4, 768, 0, stream>>>(n1a, g1, n2a, g2, amax, qvec);
  quant_w_k<<<(R_*D_+255)/256, 256, 0, stream>>>(w1vt, W1VT, R_*D_, amax + 4);
  quant_w_k<<<(H_*R_+255)/256, 256, 0, stream>>>(w1u,  W1U,  H_*R_, amax + 5);
  quant_w_k<<<(R_*H_+255)/256, 256, 0, stream>>>(w2vt, W2VT, R_*H_, amax + 6);
  quant_w_k<<<(D_*R_+255)/256, 256, 0, stream>>>(w2u,  W2U,  D_*R_, amax + 7);
  quant_attn_k<<<256, 256, 0, stream>>>(attw, WQA, amax + 1);
  stageA_k<<<dim3(12, 4, 128), 256, 0, stream>>>(x, qvec, n1b, actS, A0T);

  // attn: per-batch Out[d,m] = sum_n A0T[b][d][n] * WQA[m][n]; fused through act3
  GemmParams pa = {};
  pa.A = A0T; pa.W = WQA; pa.K = 256; pa.MT = 6; pa.NT = 2;
  pa.batchStrideA = (long)D_*256;
  pa.actS = actS; pa.amax = amax; pa.amaxIdx = 1; pa.sInIdx = 0;
  pa.bias = attb; pa.xorg = x;
  pa.qg1 = qvec + 768; pa.qn2a = qvec + 1536; pa.n2b = n2b;
  pa.X1q = X1Q; pa.A2 = A2;
  gemm_i8<0><<<dim3(12, 128), 256, 0, stream>>>(pa);

  // fc1_VT: [25088,768] x [384,768]^T -> q4
  GemmParams p1 = {};
  p1.A = A2; p1.W = W1VT; p1.K = D_; p1.MT = TOK/128; p1.NT = R_/128;
  p1.actS = actS; p1.amax = amax; p1.amaxIdx = 4; p1.sInIdx = 2; p1.sOutIdx = 4;
  p1.bias = b1vt; p1.out8 = A4; p1.ldOut = R_;
  gemm_i8<1><<<dim3((TOK/128)*(R_/128)), 256, 0, stream>>>(p1);

  // fc1_U: [25088,384] x [3072,384]^T -> q5 -> GELU -> q6
  GemmParams p2 = {};
  p2.A = A4; p2.W = W1U; p2.K = R_; p2.MT = TOK/128; p2.NT = H_/128;
  p2.actS = actS; p2.amax = amax; p2.amaxIdx = 5; p2.sInIdx = 4; p2.sOutIdx = 5; p2.sOut2Idx = 6;
  p2.bias = b1u; p2.out8 = A6; p2.ldOut = H_;
  gemm_i8<2><<<dim3((TOK/128)*(H_/128)), 256, 0, stream>>>(p2);

  // fc2_VT: [25088,3072] x [384,3072]^T -> q7
  GemmParams p3 = {};
  p3.A = A6; p3.W = W2VT; p3.K = H_; p3.MT = TOK/128; p3.NT = R_/128;
  p3.actS = actS; p3.amax = amax; p3.amaxIdx = 6; p3.sInIdx = 6; p3.sOutIdx = 7;
  p3.bias = b2vt; p3.out8 = A7; p3.ldOut = R_;
  gemm_i8<1><<<dim3((TOK/128)*(R_/128)), 256, 0, stream>>>(p3);

  // fc2_U: [25088,384] x [768,384]^T -> q3 -> gamma2 -> +x1 -> q9 -> out fp32
  GemmParams p4 = {};
  p4.A = A7; p4.W = W2U; p4.K = R_; p4.MT = TOK/128; p4.NT = D_/128;
  p4.actS = actS; p4.amax = amax; p4.amaxIdx = 7; p4.sInIdx = 7;
  p4.bias = b2u; p4.qg2 = qvec + 2304; p4.X1qIn = X1Q; p4.outF = out; p4.ldOut = D_;
  gemm_i8<3><<<dim3((TOK/128)*(D_/128)), 256, 0, stream>>>(p4);
}

// Round 2
// 540.558 us; speedup vs baseline: 1.1121x; 1.1121x over previous
//
#include <hip/hip_runtime.h>
#include <cstdint>
#include <cmath>

// Problem dims
#define B_   128
#define N_   196
#define D_   768
#define H_   3072
#define R_   384
#define TOK  (B_*N_)      // 25088

typedef int i32x4 __attribute__((ext_vector_type(4)));

// ---------------- workspace layout (bytes) ----------------
// peak ~118 MiB; A6 overlays A0T (dead after attn) by design.
#define OFF_AMAX   0L
#define OFF_LUT    512L                  // 256-entry int8 GELU LUT
#define OFF_QVEC   1024L                 // 4 x 768 fp32 quantized vectors
#define OFF_WQA    (16L*1024)            // attn weight int8 padded [256][256]
#define OFF_W1VT   (128L*1024)           // [384][768]
#define OFF_W1U    (512L*1024)           // [3072][384]
#define OFF_W2VT   (2L*1024*1024)        // [384][3072]
#define OFF_W2U    (3328L*1024)          // [768][384]
#define OFF_X1Q    (4L*1024*1024)        // int8 [25088][768]
#define OFF_A4     (24L*1024*1024)       // int8 [25088][384]
#define OFF_A7     (34L*1024*1024)       // int8 [25088][384]
#define OFF_A0T    (44L*1024*1024)       // int8 [128][768][256] (dead after attn)
#define OFF_A2     (68L*1024*1024)       // int8 [25088][768]    (dead after fc1_vt)
#define OFF_A6     (44L*1024*1024)       // int8 [25088][3072]   (overlays A0T+A2)

__device__ __forceinline__ float rclipf(float v) {
  // clip(round_half_even(v), -128, 127) ; matches jnp.clip(jnp.round(x),-n,n-1)
  return fminf(fmaxf(rintf(v), -128.f), 127.f);
}

// ---------------- absmax over 9 weight tensors ----------------
__global__ void absmax_k(const float* p0, const float* p1, const float* p2,
                         const float* p3, const float* p4, const float* p5,
                         const float* p6, const float* p7, const float* p8,
                         float* amax) {
  int tsel = blockIdx.y;
  const float* src; int n;
  switch (tsel) {
    case 0: src = p0; n = 768;     break;  // norm1_a
    case 1: src = p1; n = N_*N_;   break;  // attn_w
    case 2: src = p2; n = 768;     break;  // gamma1
    case 3: src = p3; n = 768;     break;  // norm2_a
    case 4: src = p4; n = R_*D_;   break;  // fc1_vt_w
    case 5: src = p5; n = H_*R_;   break;  // fc1_u_w
    case 6: src = p6; n = R_*H_;   break;  // fc2_vt_w
    case 7: src = p7; n = D_*R_;   break;  // fc2_u_w
    default: src = p8; n = 768;    break;  // gamma2
  }
  float m = 0.f;
  for (int i = blockIdx.x*blockDim.x + threadIdx.x; i < n; i += gridDim.x*blockDim.x)
    m = fmaxf(m, fabsf(src[i]));
  #pragma unroll
  for (int off = 32; off > 0; off >>= 1)
    m = fmaxf(m, __shfl_down(m, off));
  if ((threadIdx.x & 63) == 0)
    atomicMax((int*)(amax + tsel), __float_as_int(m));  // non-negative floats: int order == float order
}

// ---------------- quantize the 4 affine vectors (forward value, fp32) ----------------
__global__ void quant_vec_k(const float* n1a, const float* g1, const float* n2a,
                            const float* g2, const float* amax, float* dst) {
  int tsel = blockIdx.x, i = threadIdx.x;  // 768 threads
  const float* src; int ai;
  switch (tsel) {
    case 0: src = n1a; ai = 0; break;
    case 1: src = g1;  ai = 2; break;
    case 2: src = n2a; ai = 3; break;
    default: src = g2; ai = 8; break;
  }
  float s = amax[ai] / 127.f + 1e-8f;
  dst[tsel*768 + i] = s * rclipf(src[i] / s);
}

// ---------------- GELU LUT: q5 (int8) -> q6 (int8), bit-identical to erff path ----------------
__global__ void gelu_lut_k(const float* actS, int8_t* lut) {
  int t = threadIdx.x;             // 0..255
  float s5 = actS[5], s6 = actS[6];
  float v5 = s5 * (float)(t - 128);
  float g  = 0.5f * v5 * (1.f + erff(v5 * 0.70710678118654752f));
  lut[t] = (int8_t)(int)rclipf(g / s6);
}

// ---------------- quantize a matmul weight to int8 ----------------
__global__ void quant_w_k(const float* w, int8_t* dst, int n, const float* amaxp) {
  int i = blockIdx.x*blockDim.x + threadIdx.x;
  if (i >= n) return;
  float s = *amaxp / 127.f + 1e-8f;
  dst[i] = (int8_t)(int)rclipf(w[i] / s);
}

// attn weight: quantize + zero-pad into [256][256]
__global__ void quant_attn_k(const float* w, int8_t* dst, const float* amaxp) {
  int i = blockIdx.x*blockDim.x + threadIdx.x;  // 65536
  int m = i >> 8, n = i & 255;
  float s = *amaxp / 127.f + 1e-8f;
  int8_t q = 0;
  if (m < N_ && n < N_) q = (int8_t)(int)rclipf(w[m*N_ + n] / s);
  dst[i] = q;
}

// ---------------- stage A: norm1 affine + act-quant, transposed to A0T[b][d][n256] ----------------
__global__ void stageA_k(const float* __restrict__ x, const float* __restrict__ qn1a,
                         const float* __restrict__ n1b, const float* __restrict__ actS,
                         int8_t* __restrict__ A0T) {
  __shared__ int8_t ldsT[64*68];   // [d][n] tile, pad 68 keeps u32 align + conflict-free
  const int dt = blockIdx.x;   // 0..11 (d tile of 64)
  const int nt = blockIdx.y;   // 0..3  (n tile of 64, n padded to 256)
  const int b  = blockIdx.z;
  const float s0 = actS[0];
  const int d0 = dt*64, n0 = nt*64;
  const int tid = threadIdx.x;
  const int dc = tid & 63, nr4 = tid >> 6;
  const float qa = qn1a[d0 + dc];
  const float bb = n1b[d0 + dc];
  #pragma unroll 4
  for (int it = 0; it < 16; ++it) {
    int nl = nr4 + it*4;
    int n = n0 + nl;
    int8_t q = 0;
    if (n < N_) {
      float v = x[((long)b*N_ + n)*D_ + d0 + dc] * qa + bb;
      q = (int8_t)(int)rclipf(v / s0);
    }
    ldsT[dc*68 + nl] = q;
  }
  __syncthreads();
  const int k = tid & 15, dr = tid >> 4;
  #pragma unroll
  for (int it = 0; it < 4; ++it) {
    int d = dr + it*16;
    uint32_t v = *(const uint32_t*)(&ldsT[d*68 + k*4]);
    *(uint32_t*)(&A0T[(long)b*(D_*256) + (long)(d0+d)*256 + n0 + k*4]) = v;
  }
}

// ---------------- generic i8 GEMM: Out[i,j] = sum_k A[i,k]*W[j,k] ----------------
// BM=BN=128, BK=64; 4 waves, each 64x64 via 4x4 of mfma_i32_16x16x64_i8.
// Epilogues: 0=attn(+gamma1+res+norm2+act3), 1=plain quant, 2=quant+LUT(GELU), 3=final.
struct GemmParams {
  const int8_t* A;
  const int8_t* W;
  int K, MT, NT;
  long batchStrideA;
  const float* actS;
  const float* amax;
  int amaxIdx, sInIdx, sOutIdx, sOut2Idx;
  const float* bias;
  int8_t* out8;
  int ldOut;
  // attn epilogue
  const float* xorg;
  const float* qg1;
  const float* qn2a;
  const float* n2b;
  int8_t* X1q;
  int8_t* A2;
  // final epilogue
  const float* qg2;
  const int8_t* X1qIn;
  float* outF;
  // EPI=2
  const int8_t* lutG;
};

template<int EPI>
__launch_bounds__(256, 2)
__global__ void gemm_i8(GemmParams p) {
  __shared__ __align__(16) int8_t lsA[2][128][80];   // pad 80B row: 2-way LDS conflicts (free)
  __shared__ __align__(16) int8_t lsB[2][128][80];
  __shared__ int8_t lut[256];
  const int K  = p.K;
  const int bx = blockIdx.x;
  const int mt = bx % p.MT;
  const int nt = bx / p.MT;
  const int t    = threadIdx.x;
  const int wid  = t >> 6;
  const int lane = t & 63;
  const int wm = wid & 1, wn = wid >> 1;
  const int quad = lane >> 4, l15 = lane & 15;

  if constexpr (EPI == 2) lut[t] = p.lutG[t];   // ordered by the prologue __syncthreads

  const int8_t* Abase = p.A + (long)blockIdx.y * p.batchStrideA + (long)mt*128*K;
  const int8_t* Wbase = p.W + (long)nt*128*K;

  const int ar = t >> 2;         // 0..63 (row), +64 for second half
  const int ac = (t & 3) * 16;   // 16B chunk within the 64B k-slice

  i32x4 ra0, ra1, rb0, rb1;
  auto gload = [&](int k0) {
    ra0 = *(const i32x4*)(Abase + (long)ar*K       + k0 + ac);
    ra1 = *(const i32x4*)(Abase + (long)(ar+64)*K  + k0 + ac);
    rb0 = *(const i32x4*)(Wbase + (long)ar*K       + k0 + ac);
    rb1 = *(const i32x4*)(Wbase + (long)(ar+64)*K  + k0 + ac);
  };
  auto lstore = [&](int buf) {
    *(i32x4*)(&lsA[buf][ar][ac])    = ra0;
    *(i32x4*)(&lsA[buf][ar+64][ac]) = ra1;
    *(i32x4*)(&lsB[buf][ar][ac])    = rb0;
    *(i32x4*)(&lsB[buf][ar+64][ac]) = rb1;
  };

  const i32x4 zero = {0, 0, 0, 0};
  i32x4 acc[4][4];
  #pragma unroll
  for (int i = 0; i < 4; ++i)
    #pragma unroll
    for (int j = 0; j < 4; ++j) acc[i][j] = zero;

  gload(0); lstore(0); __syncthreads();
  const int KT = K >> 6;
  for (int kt = 0; kt < KT; ++kt) {
    const int cur = kt & 1;
    if (kt + 1 < KT) gload((kt + 1) << 6);   // async-ish: vmcnt waited at lstore
    i32x4 af[4], bf[4];
    #pragma unroll
    for (int i = 0; i < 4; ++i)
      af[i] = *(const i32x4*)(&lsA[cur][wm*64 + i*16 + l15][quad*16]);
    #pragma unroll
    for (int j = 0; j < 4; ++j)
      bf[j] = *(const i32x4*)(&lsB[cur][wn*64 + j*16 + l15][quad*16]);
    #pragma unroll
    for (int i = 0; i < 4; ++i)
      #pragma unroll
      for (int j = 0; j < 4; ++j)
        acc[i][j] = __builtin_amdgcn_mfma_i32_16x16x64_i8(af[i], bf[j], acc[i][j], 0, 0, 0);
    if (kt + 1 < KT) { lstore(cur ^ 1); __syncthreads(); }
  }

  // ---- epilogue ---- C/D layout (16x16, m89-verified): col=lane&15, row=quad*4+reg
  const float sW  = p.amax[p.amaxIdx] / 127.f + 1e-8f;
  const float sAB = p.actS[p.sInIdx] * sW;
  const int i0 = mt*128 + wm*64;
  const int j0 = nt*128 + wn*64;

  #pragma unroll
  for (int ii = 0; ii < 4; ++ii) {
    #pragma unroll
    for (int jj = 0; jj < 4; ++jj) {
      const int i = i0 + ii*16 + quad*4;   // GEMM row
      const int j = j0 + jj*16 + l15;      // GEMM col
      if constexpr (EPI == 0) {
        // i = d (0..767), j = m patch (guard <196), batch = blockIdx.y
        if (j < N_) {
          const float s1v = p.actS[1], s8v = p.actS[8], s2v = p.actS[2];
          const float bj = p.bias[j];
          const long tok = (long)blockIdx.y * N_ + j;
          const float4 xo = *(const float4*)(p.xorg + tok*D_ + i);
          uint32_t pk8 = 0, pk2 = 0;
          #pragma unroll
          for (int r = 0; r < 4; ++r) {
            float v  = sAB * (float)acc[ii][jj][r] + bj;          // attn out + bias
            float q1 = rclipf(v / s1v);                           // act2
            float h  = s1v * q1 * p.qg1[i+r];                     // gamma_1
            float rs = h + ((const float*)&xo)[r];                // + org
            float q8 = rclipf(rs / s8v);                          // add_1 (res 8-bit)
            float x1 = s8v * q8;
            float t2 = x1 * p.qn2a[i+r] + p.n2b[i+r];             // norm2
            float q2 = rclipf(t2 / s2v);                          // act3
            pk8 |= ((uint32_t)(uint8_t)(int8_t)(int)q8) << (8*r);
            pk2 |= ((uint32_t)(uint8_t)(int8_t)(int)q2) << (8*r);
          }
          *(uint32_t*)(p.X1q + tok*D_ + i) = pk8;
          *(uint32_t*)(p.A2  + tok*D_ + i) = pk2;
        }
      } else if constexpr (EPI == 1) {
        const float sO = p.actS[p.sOutIdx];
        const float bj = p.bias[j];
        #pragma unroll
        for (int r = 0; r < 4; ++r) {
          float v = sAB * (float)acc[ii][jj][r] + bj;
          p.out8[(long)(i+r)*p.ldOut + j] = (int8_t)(int)rclipf(v / sO);
        }
      } else if constexpr (EPI == 2) {
        const float s5v = p.actS[p.sOutIdx];
        const float bj = p.bias[j];
        #pragma unroll
        for (int r = 0; r < 4; ++r) {
          float v  = sAB * (float)acc[ii][jj][r] + bj;
          int q5 = (int)rclipf(v / s5v) + 128;                    // act2 index
          p.out8[(long)(i+r)*p.ldOut + j] = lut[q5];              // GELU+act3 via LUT
        }
      } else {
        const float s3v = p.actS[3], s8v = p.actS[8], s9v = p.actS[9];
        const float bj = p.bias[j];
        const float g2 = p.qg2[j];
        #pragma unroll
        for (int r = 0; r < 4; ++r) {
          long idx = (long)(i+r)*D_ + j;
          float v  = sAB * (float)acc[ii][jj][r] + bj;
          float q3 = rclipf(v / s3v);                             // block act4
          float h  = s3v * q3 * g2;                               // gamma_2
          float o  = h + s8v * (float)p.X1qIn[idx];               // + org (x1)
          p.outF[idx] = s9v * rclipf(o / s9v);                    // add_2
        }
      }
    }
  }
}

// ---------------- host launch ----------------
extern "C" void kernel_launch(void* const* d_in, const int* in_sizes, int n_in,
                              void* d_out, int out_size, void* d_ws, size_t ws_size,
                              hipStream_t stream) {
  (void)in_sizes; (void)n_in; (void)out_size; (void)ws_size;
  const float* x    = (const float*)d_in[0];
  const float* n1a  = (const float*)d_in[1];
  const float* n1b  = (const float*)d_in[2];
  const float* attw = (const float*)d_in[3];
  const float* attb = (const float*)d_in[4];
  const float* g1   = (const float*)d_in[5];
  const float* n2a  = (const float*)d_in[6];
  const float* n2b  = (const float*)d_in[7];
  const float* w1vt = (const float*)d_in[8];
  const float* b1vt = (const float*)d_in[9];
  const float* w1u  = (const float*)d_in[10];
  const float* b1u  = (const float*)d_in[11];
  const float* w2vt = (const float*)d_in[12];
  const float* b2vt = (const float*)d_in[13];
  const float* w2u  = (const float*)d_in[14];
  const float* b2u  = (const float*)d_in[15];
  const float* g2   = (const float*)d_in[16];
  const float* actS = (const float*)d_in[17];
  float* out = (float*)d_out;
  char* ws = (char*)d_ws;

  float*  amax = (float*)(ws + OFF_AMAX);
  int8_t* LUTG = (int8_t*)(ws + OFF_LUT);
  float*  qvec = (float*)(ws + OFF_QVEC);
  int8_t* WQA  = (int8_t*)(ws + OFF_WQA);
  int8_t* W1VT = (int8_t*)(ws + OFF_W1VT);
  int8_t* W1U  = (int8_t*)(ws + OFF_W1U);
  int8_t* W2VT = (int8_t*)(ws + OFF_W2VT);
  int8_t* W2U  = (int8_t*)(ws + OFF_W2U);
  int8_t* X1Q  = (int8_t*)(ws + OFF_X1Q);
  int8_t* A4   = (int8_t*)(ws + OFF_A4);
  int8_t* A7   = (int8_t*)(ws + OFF_A7);
  int8_t* A0T  = (int8_t*)(ws + OFF_A0T);
  int8_t* A2   = (int8_t*)(ws + OFF_A2);
  int8_t* A6   = (int8_t*)(ws + OFF_A6);

  hipMemsetAsync(amax, 0, 64, stream);
  absmax_k<<<dim3(32, 9), 256, 0, stream>>>(n1a, attw, g1, n2a, w1vt, w1u, w2vt, w2u, g2, amax);
  quant_vec_k<<<4, 768, 0, stream>>>(n1a, g1, n2a, g2, amax, qvec);
  gelu_lut_k<<<1, 256, 0, stream>>>(actS, LUTG);
  quant_w_k<<<(R_*D_+255)/256, 256, 0, stream>>>(w1vt, W1VT, R_*D_, amax + 4);
  quant_w_k<<<(H_*R_+255)/256, 256, 0, stream>>>(w1u,  W1U,  H_*R_, amax + 5);
  quant_w_k<<<(R_*H_+255)/256, 256, 0, stream>>>(w2vt, W2VT, R_*H_, amax + 6);
  quant_w_k<<<(D_*R_+255)/256, 256, 0, stream>>>(w2u,  W2U,  D_*R_, amax + 7);
  quant_attn_k<<<256, 256, 0, stream>>>(attw, WQA, amax + 1);
  stageA_k<<<dim3(12, 4, 128), 256, 0, stream>>>(x, qvec, n1b, actS, A0T);

  // attn: per-batch Out[d,m] = sum_n A0T[b][d][n] * WQA[m][n]; fused through act3
  GemmParams pa = {};
  pa.A = A0T; pa.W = WQA; pa.K = 256; pa.MT = 6; pa.NT = 2;
  pa.batchStrideA = (long)D_*256;
  pa.actS = actS; pa.amax = amax; pa.amaxIdx = 1; pa.sInIdx = 0;
  pa.bias = attb; pa.xorg = x;
  pa.qg1 = qvec + 768; pa.qn2a = qvec + 1536; pa.n2b = n2b;
  pa.X1q = X1Q; pa.A2 = A2;
  gemm_i8<0><<<dim3(12, 128), 256, 0, stream>>>(pa);

  // fc1_VT: [25088,768] x [384,768]^T -> q4
  GemmParams p1 = {};
  p1.A = A2; p1.W = W1VT; p1.K = D_; p1.MT = TOK/128; p1.NT = R_/128;
  p1.actS = actS; p1.amax = amax; p1.amaxIdx = 4; p1.sInIdx = 2; p1.sOutIdx = 4;
  p1.bias = b1vt; p1.out8 = A4; p1.ldOut = R_;
  gemm_i8<1><<<dim3((TOK/128)*(R_/128)), 256, 0, stream>>>(p1);

  // fc1_U: [25088,384] x [3072,384]^T -> q5 -> GELU -> q6 (fused as int8 LUT)
  GemmParams p2 = {};
  p2.A = A4; p2.W = W1U; p2.K = R_; p2.MT = TOK/128; p2.NT = H_/128;
  p2.actS = actS; p2.amax = amax; p2.amaxIdx = 5; p2.sInIdx = 4; p2.sOutIdx = 5; p2.sOut2Idx = 6;
  p2.bias = b1u; p2.out8 = A6; p2.ldOut = H_; p2.lutG = LUTG;
  gemm_i8<2><<<dim3((TOK/128)*(H_/128)), 256, 0, stream>>>(p2);

  // fc2_VT: [25088,3072] x [384,3072]^T -> q7
  GemmParams p3 = {};
  p3.A = A6; p3.W = W2VT; p3.K = H_; p3.MT = TOK/128; p3.NT = R_/128;
  p3.actS = actS; p3.amax = amax; p3.amaxIdx = 6; p3.sInIdx = 6; p3.sOutIdx = 7;
  p3.bias = b2vt; p3.out8 = A7; p3.ldOut = R_;
  gemm_i8<1><<<dim3((TOK/128)*(R_/128)), 256, 0, stream>>>(p3);

  // fc2_U: [25088,384] x [768,384]^T -> q3 -> gamma2 -> +x1 -> q9 -> out fp32
  GemmParams p4 = {};
  p4.A = A7; p4.W = W2U; p4.K = R_; p4.MT = TOK/128; p4.NT = D_/128;
  p4.actS = actS; p4.amax = amax; p4.amaxIdx = 7; p4.sInIdx = 7;
  p4.bias = b2u; p4.qg2 = qvec + 2304; p4.X1qIn = X1Q; p4.outF = out; p4.ldOut = D_;
  gemm_i8<3><<<dim3((TOK/128)*(D_/128)), 256, 0, stream>>>(p4);
}

// Round 3
// 525.200 us; speedup vs baseline: 1.1446x; 1.0292x over previous
//
#include <hip/hip_runtime.h>
#include <cstdint>
#include <cmath>

// Problem dims
#define B_   128
#define N_   196
#define D_   768
#define H_   3072
#define R_   384
#define TOK  (B_*N_)      // 25088

typedef int i32x4 __attribute__((ext_vector_type(4)));

// ---------------- workspace layout (bytes) ----------------
#define OFF_AMAX   0L
#define OFF_LUT    512L                  // 256-entry int8 GELU LUT
#define OFF_QVEC   1024L                 // 6 x 768 fp32 precomputed epilogue vectors
#define OFF_WQA    (32L*1024)            // attn weight int8 padded [256][256]
#define OFF_W1VT   (128L*1024)           // [384][768]
#define OFF_W1U    (512L*1024)           // [3072][384]
#define OFF_W2VT   (2L*1024*1024)        // [384][3072]
#define OFF_W2U    (3328L*1024)          // [768][384]
#define OFF_X1Q    (4L*1024*1024)        // int8 [25088][768]
#define OFF_A4     (24L*1024*1024)       // int8 [25088][384]
#define OFF_A7     (34L*1024*1024)       // int8 [25088][384]
#define OFF_A0T    (44L*1024*1024)       // int8 [128][768][256] (dead after attn)
#define OFF_A2     (68L*1024*1024)       // int8 [25088][768]    (dead after fc1_vt)
#define OFF_A6     (44L*1024*1024)       // int8 [25088][3072]   (overlays A0T+A2)

__device__ __forceinline__ float rclipf(float v) {
  // clip(round_half_even(v), -128, 127) ; matches jnp.clip(jnp.round(x),-n,n-1)
  return fminf(fmaxf(rintf(v), -128.f), 127.f);
}

// ---------------- absmax over 9 weight tensors ----------------
__global__ void absmax_k(const float* p0, const float* p1, const float* p2,
                         const float* p3, const float* p4, const float* p5,
                         const float* p6, const float* p7, const float* p8,
                         float* amax) {
  int tsel = blockIdx.y;
  const float* src; int n;
  switch (tsel) {
    case 0: src = p0; n = 768;     break;  // norm1_a
    case 1: src = p1; n = N_*N_;   break;  // attn_w
    case 2: src = p2; n = 768;     break;  // gamma1
    case 3: src = p3; n = 768;     break;  // norm2_a
    case 4: src = p4; n = R_*D_;   break;  // fc1_vt_w
    case 5: src = p5; n = H_*R_;   break;  // fc1_u_w
    case 6: src = p6; n = R_*H_;   break;  // fc2_vt_w
    case 7: src = p7; n = D_*R_;   break;  // fc2_u_w
    default: src = p8; n = 768;    break;  // gamma2
  }
  float m = 0.f;
  for (int i = blockIdx.x*blockDim.x + threadIdx.x; i < n; i += gridDim.x*blockDim.x)
    m = fmaxf(m, fabsf(src[i]));
  #pragma unroll
  for (int off = 32; off > 0; off >>= 1)
    m = fmaxf(m, __shfl_down(m, off));
  if ((threadIdx.x & 63) == 0)
    atomicMax((int*)(amax + tsel), __float_as_int(m));  // non-negative floats: int order == float order
}

// ---------------- precompute fused epilogue vectors (768 threads, 1 block) ----------------
// dst layout (floats): [0]=n1as=qn1a/s0  [768]=n1bs=n1b/s0  [1536]=g1s=s1*qg1/s8
//                      [2304]=a2s8=s8*qn2a/s2  [3072]=b2s=n2b/s2  [3840]=g2s9=s3*qg2/s9
__global__ void prep_vec_k(const float* n1a, const float* n1b, const float* g1,
                           const float* n2a, const float* n2b, const float* g2,
                           const float* amax, const float* actS, float* dst) {
  int i = threadIdx.x;  // 768
  float s0 = actS[0], s1 = actS[1], s2 = actS[2], s3 = actS[3];
  float s8 = actS[8], s9 = actS[9];
  float sw;
  sw = amax[0]/127.f + 1e-8f; float qn1a = sw * rclipf(n1a[i]/sw);
  dst[i]        = qn1a / s0;
  dst[768+i]    = n1b[i] / s0;
  sw = amax[2]/127.f + 1e-8f; float qg1 = sw * rclipf(g1[i]/sw);
  dst[1536+i]   = (s1 * qg1) / s8;
  sw = amax[3]/127.f + 1e-8f; float qn2a = sw * rclipf(n2a[i]/sw);
  dst[2304+i]   = (s8 * qn2a) / s2;
  dst[3072+i]   = n2b[i] / s2;
  sw = amax[8]/127.f + 1e-8f; float qg2 = sw * rclipf(g2[i]/sw);
  dst[3840+i]   = (s3 * qg2) / s9;
}

// ---------------- GELU LUT: q5 (int8) -> q6 (int8), bit-identical to erff path ----------------
__global__ void gelu_lut_k(const float* actS, int8_t* lut) {
  int t = threadIdx.x;             // 0..255
  float s5 = actS[5], s6 = actS[6];
  float v5 = s5 * (float)(t - 128);
  float g  = 0.5f * v5 * (1.f + erff(v5 * 0.70710678118654752f));
  lut[t] = (int8_t)(int)rclipf(g / s6);
}

// ---------------- quantize a matmul weight to int8 ----------------
__global__ void quant_w_k(const float* w, int8_t* dst, int n, const float* amaxp) {
  int i = blockIdx.x*blockDim.x + threadIdx.x;
  if (i >= n) return;
  float s = *amaxp / 127.f + 1e-8f;
  dst[i] = (int8_t)(int)rclipf(w[i] / s);
}

// attn weight: quantize + zero-pad into [256][256]
__global__ void quant_attn_k(const float* w, int8_t* dst, const float* amaxp) {
  int i = blockIdx.x*blockDim.x + threadIdx.x;  // 65536
  int m = i >> 8, n = i & 255;
  float s = *amaxp / 127.f + 1e-8f;
  int8_t q = 0;
  if (m < N_ && n < N_) q = (int8_t)(int)rclipf(w[m*N_ + n] / s);
  dst[i] = q;
}

// ---------------- stage A: norm1 affine + act-quant, transposed to A0T[b][d][n256] ----------------
__global__ void stageA_k(const float* __restrict__ x, const float* __restrict__ n1as,
                         const float* __restrict__ n1bs, int8_t* __restrict__ A0T) {
  __shared__ int8_t ldsT[64*68];   // [d][n] tile, pad 68 keeps u32 align + conflict-free
  const int dt = blockIdx.x;   // 0..11 (d tile of 64)
  const int nt = blockIdx.y;   // 0..3  (n tile of 64, n padded to 256)
  const int b  = blockIdx.z;
  const int d0 = dt*64, n0 = nt*64;
  const int tid = threadIdx.x;
  const int dc = tid & 63, nr4 = tid >> 6;
  const float qa = n1as[d0 + dc];
  const float bb = n1bs[d0 + dc];
  #pragma unroll 4
  for (int it = 0; it < 16; ++it) {
    int nl = nr4 + it*4;
    int n = n0 + nl;
    int8_t q = 0;
    if (n < N_) {
      float v = fmaf(x[((long)b*N_ + n)*D_ + d0 + dc], qa, bb);
      q = (int8_t)(int)rclipf(v);
    }
    ldsT[dc*68 + nl] = q;
  }
  __syncthreads();
  const int k = tid & 15, dr = tid >> 4;
  #pragma unroll
  for (int it = 0; it < 4; ++it) {
    int d = dr + it*16;
    uint32_t v = *(const uint32_t*)(&ldsT[d*68 + k*4]);
    *(uint32_t*)(&A0T[(long)b*(D_*256) + (long)(d0+d)*256 + n0 + k*4]) = v;
  }
}

// ---------------- generic i8 GEMM: Out[i,j] = sum_k A[i,k]*W[j,k] ----------------
// BM=BN=128, BK=64; 4 waves, each 64x64 via 4x4 of mfma_i32_16x16x64_i8.
// Epilogues: 0=attn(+gamma1+res+norm2+act3), 1=plain quant, 2=quant+LUT(GELU), 3=final.
// All quant chains fused as integer-fma: rclip(acc*(sAB/s) + b/s) — no per-element fdiv.
struct GemmParams {
  const int8_t* A;
  const int8_t* W;
  int K, MT, NT;
  long batchStrideA;
  const float* actS;
  const float* amax;
  int amaxIdx, sInIdx, sOutIdx, sOut2Idx;
  const float* bias;
  int8_t* out8;
  int ldOut;
  // attn epilogue (EPI=0): g1s / a2s8 / b2s vectors
  const float* xorg;
  const float* g1s;
  const float* a2s8;
  const float* b2s;
  int8_t* X1q;
  int8_t* A2;
  // final epilogue (EPI=3)
  const float* g2s9;
  const int8_t* X1qIn;
  float* outF;
  // EPI=2
  const int8_t* lutG;
};

template<int EPI>
__launch_bounds__(256, 3)
__global__ void gemm_i8(GemmParams p) {
  __shared__ __align__(16) int8_t lsA[2][128][80];   // pad 80B row: optimal spread for b128
  __shared__ __align__(16) int8_t lsB[2][128][80];
  __shared__ int8_t lut[256];
  const int K  = p.K;
  const int bx = blockIdx.x;
  const int mt = bx % p.MT;
  const int nt = bx / p.MT;
  const int t    = threadIdx.x;
  const int wid  = t >> 6;
  const int lane = t & 63;
  const int wm = wid & 1, wn = wid >> 1;
  const int quad = lane >> 4, l15 = lane & 15;

  if constexpr (EPI == 2) lut[t] = p.lutG[t];   // ordered by the prologue __syncthreads

  const int8_t* Abase = p.A + (long)blockIdx.y * p.batchStrideA + (long)mt*128*K;
  const int8_t* Wbase = p.W + (long)nt*128*K;

  const int ar = t >> 2;         // 0..63 (row), +64 for second half
  const int ac = (t & 3) * 16;   // 16B chunk within the 64B k-slice

  i32x4 ra0, ra1, rb0, rb1;
  auto gload = [&](int k0) {
    ra0 = *(const i32x4*)(Abase + (long)ar*K       + k0 + ac);
    ra1 = *(const i32x4*)(Abase + (long)(ar+64)*K  + k0 + ac);
    rb0 = *(const i32x4*)(Wbase + (long)ar*K       + k0 + ac);
    rb1 = *(const i32x4*)(Wbase + (long)(ar+64)*K  + k0 + ac);
  };
  auto lstore = [&](int buf) {
    *(i32x4*)(&lsA[buf][ar][ac])    = ra0;
    *(i32x4*)(&lsA[buf][ar+64][ac]) = ra1;
    *(i32x4*)(&lsB[buf][ar][ac])    = rb0;
    *(i32x4*)(&lsB[buf][ar+64][ac]) = rb1;
  };

  const i32x4 zero = {0, 0, 0, 0};
  i32x4 acc[4][4];
  #pragma unroll
  for (int i = 0; i < 4; ++i)
    #pragma unroll
    for (int j = 0; j < 4; ++j) acc[i][j] = zero;

  gload(0); lstore(0); __syncthreads();
  const int KT = K >> 6;
  for (int kt = 0; kt < KT; ++kt) {
    const int cur = kt & 1;
    if (kt + 1 < KT) gload((kt + 1) << 6);   // async-ish: vmcnt waited at lstore
    i32x4 af[4], bf[4];
    #pragma unroll
    for (int i = 0; i < 4; ++i)
      af[i] = *(const i32x4*)(&lsA[cur][wm*64 + i*16 + l15][quad*16]);
    #pragma unroll
    for (int j = 0; j < 4; ++j)
      bf[j] = *(const i32x4*)(&lsB[cur][wn*64 + j*16 + l15][quad*16]);
    #pragma unroll
    for (int i = 0; i < 4; ++i)
      #pragma unroll
      for (int j = 0; j < 4; ++j)
        acc[i][j] = __builtin_amdgcn_mfma_i32_16x16x64_i8(af[i], bf[j], acc[i][j], 0, 0, 0);
    if (kt + 1 < KT) { lstore(cur ^ 1); __syncthreads(); }
  }

  // ---- epilogue ---- C/D layout (16x16, m89-verified): col=lane&15, row=quad*4+reg
  const float sW  = p.amax[p.amaxIdx] / 127.f + 1e-8f;
  const float sAB = p.actS[p.sInIdx] * sW;
  const int i0 = mt*128 + wm*64;
  const int j0 = nt*128 + wn*64;

  #pragma unroll
  for (int ii = 0; ii < 4; ++ii) {
    const int i = i0 + ii*16 + quad*4;   // GEMM row
    if constexpr (EPI == 0) {
      // i = d (0..767), j = m patch (guard <196), batch = blockIdx.y
      const float c1     = sAB / p.actS[1];
      const float inv_s8 = 1.f / p.actS[8];
      const float4 g1s4 = *(const float4*)(p.g1s + i);
      const float4 a2s4 = *(const float4*)(p.a2s8 + i);
      const float4 b2s4 = *(const float4*)(p.b2s + i);
      #pragma unroll
      for (int jj = 0; jj < 4; ++jj) {
        const int j = j0 + jj*16 + l15;
        if (j < N_) {
          const float c2 = p.bias[j] / p.actS[1];
          const long tok = (long)blockIdx.y * N_ + j;
          const float4 xo = *(const float4*)(p.xorg + tok*D_ + i);
          uint32_t pk8 = 0, pk2 = 0;
          #pragma unroll
          for (int r = 0; r < 4; ++r) {
            float accf = (float)acc[ii][jj][r];
            float q1 = rclipf(fmaf(accf, c1, c2));                               // act2
            float q8 = rclipf(fmaf(q1, ((const float*)&g1s4)[r],
                                   ((const float*)&xo)[r] * inv_s8));            // gamma1 + res
            float q2 = rclipf(fmaf(q8, ((const float*)&a2s4)[r],
                                   ((const float*)&b2s4)[r]));                   // norm2 + act3
            pk8 |= ((uint32_t)(uint8_t)(int8_t)(int)q8) << (8*r);
            pk2 |= ((uint32_t)(uint8_t)(int8_t)(int)q2) << (8*r);
          }
          *(uint32_t*)(p.X1q + tok*D_ + i) = pk8;
          *(uint32_t*)(p.A2  + tok*D_ + i) = pk2;
        }
      }
    } else if constexpr (EPI == 1) {
      const float sO = p.actS[p.sOutIdx];
      const float c1 = sAB / sO;
      #pragma unroll
      for (int jj = 0; jj < 4; ++jj) {
        const int j = j0 + jj*16 + l15;
        const float c2 = p.bias[j] / sO;
        #pragma unroll
        for (int r = 0; r < 4; ++r) {
          float q = rclipf(fmaf((float)acc[ii][jj][r], c1, c2));
          p.out8[(long)(i+r)*p.ldOut + j] = (int8_t)(int)q;
        }
      }
    } else if constexpr (EPI == 2) {
      const float s5v = p.actS[p.sOutIdx];
      const float c1 = sAB / s5v;
      #pragma unroll
      for (int jj = 0; jj < 4; ++jj) {
        const int j = j0 + jj*16 + l15;
        const float c2 = p.bias[j] / s5v;
        #pragma unroll
        for (int r = 0; r < 4; ++r) {
          int q5 = (int)rclipf(fmaf((float)acc[ii][jj][r], c1, c2)) + 128;  // act2 idx
          p.out8[(long)(i+r)*p.ldOut + j] = lut[q5];                        // GELU+act3
        }
      }
    } else {
      const float s3v = p.actS[3], s9v = p.actS[9];
      const float c1  = sAB / s3v;
      const float c89 = p.actS[8] / s9v;
      #pragma unroll
      for (int jj = 0; jj < 4; ++jj) {
        const int j = j0 + jj*16 + l15;
        const float c2  = p.bias[j] / s3v;
        const float g2s = p.g2s9[j];
        #pragma unroll
        for (int r = 0; r < 4; ++r) {
          long idx = (long)(i+r)*D_ + j;
          float q3 = rclipf(fmaf((float)acc[ii][jj][r], c1, c2));   // block act4
          float q8 = (float)p.X1qIn[idx];
          float q9 = rclipf(fmaf(q3, g2s, q8 * c89));               // gamma2 + res + add_2
          p.outF[idx] = s9v * q9;
        }
      }
    }
  }
}

// ---------------- host launch ----------------
extern "C" void kernel_launch(void* const* d_in, const int* in_sizes, int n_in,
                              void* d_out, int out_size, void* d_ws, size_t ws_size,
                              hipStream_t stream) {
  (void)in_sizes; (void)n_in; (void)out_size; (void)ws_size;
  const float* x    = (const float*)d_in[0];
  const float* n1a  = (const float*)d_in[1];
  const float* n1b  = (const float*)d_in[2];
  const float* attw = (const float*)d_in[3];
  const float* attb = (const float*)d_in[4];
  const float* g1   = (const float*)d_in[5];
  const float* n2a  = (const float*)d_in[6];
  const float* n2b  = (const float*)d_in[7];
  const float* w1vt = (const float*)d_in[8];
  const float* b1vt = (const float*)d_in[9];
  const float* w1u  = (const float*)d_in[10];
  const float* b1u  = (const float*)d_in[11];
  const float* w2vt = (const float*)d_in[12];
  const float* b2vt = (const float*)d_in[13];
  const float* w2u  = (const float*)d_in[14];
  const float* b2u  = (const float*)d_in[15];
  const float* g2   = (const float*)d_in[16];
  const float* actS = (const float*)d_in[17];
  float* out = (float*)d_out;
  char* ws = (char*)d_ws;

  float*  amax = (float*)(ws + OFF_AMAX);
  int8_t* LUTG = (int8_t*)(ws + OFF_LUT);
  float*  qvec = (float*)(ws + OFF_QVEC);
  int8_t* WQA  = (int8_t*)(ws + OFF_WQA);
  int8_t* W1VT = (int8_t*)(ws + OFF_W1VT);
  int8_t* W1U  = (int8_t*)(ws + OFF_W1U);
  int8_t* W2VT = (int8_t*)(ws + OFF_W2VT);
  int8_t* W2U  = (int8_t*)(ws + OFF_W2U);
  int8_t* X1Q  = (int8_t*)(ws + OFF_X1Q);
  int8_t* A4   = (int8_t*)(ws + OFF_A4);
  int8_t* A7   = (int8_t*)(ws + OFF_A7);
  int8_t* A0T  = (int8_t*)(ws + OFF_A0T);
  int8_t* A2   = (int8_t*)(ws + OFF_A2);
  int8_t* A6   = (int8_t*)(ws + OFF_A6);

  hipMemsetAsync(amax, 0, 64, stream);
  absmax_k<<<dim3(32, 9), 256, 0, stream>>>(n1a, attw, g1, n2a, w1vt, w1u, w2vt, w2u, g2, amax);
  prep_vec_k<<<1, 768, 0, stream>>>(n1a, n1b, g1, n2a, n2b, g2, amax, actS, qvec);
  gelu_lut_k<<<1, 256, 0, stream>>>(actS, LUTG);
  quant_w_k<<<(R_*D_+255)/256, 256, 0, stream>>>(w1vt, W1VT, R_*D_, amax + 4);
  quant_w_k<<<(H_*R_+255)/256, 256, 0, stream>>>(w1u,  W1U,  H_*R_, amax + 5);
  quant_w_k<<<(R_*H_+255)/256, 256, 0, stream>>>(w2vt, W2VT, R_*H_, amax + 6);
  quant_w_k<<<(D_*R_+255)/256, 256, 0, stream>>>(w2u,  W2U,  D_*R_, amax + 7);
  quant_attn_k<<<256, 256, 0, stream>>>(attw, WQA, amax + 1);
  stageA_k<<<dim3(12, 4, 128), 256, 0, stream>>>(x, qvec, qvec + 768, A0T);

  // attn: per-batch Out[d,m] = sum_n A0T[b][d][n] * WQA[m][n]; fused through act3
  GemmParams pa = {};
  pa.A = A0T; pa.W = WQA; pa.K = 256; pa.MT = 6; pa.NT = 2;
  pa.batchStrideA = (long)D_*256;
  pa.actS = actS; pa.amax = amax; pa.amaxIdx = 1; pa.sInIdx = 0;
  pa.bias = attb; pa.xorg = x;
  pa.g1s = qvec + 1536; pa.a2s8 = qvec + 2304; pa.b2s = qvec + 3072;
  pa.X1q = X1Q; pa.A2 = A2;
  gemm_i8<0><<<dim3(12, 128), 256, 0, stream>>>(pa);

  // fc1_VT: [25088,768] x [384,768]^T -> q4
  GemmParams p1 = {};
  p1.A = A2; p1.W = W1VT; p1.K = D_; p1.MT = TOK/128; p1.NT = R_/128;
  p1.actS = actS; p1.amax = amax; p1.amaxIdx = 4; p1.sInIdx = 2; p1.sOutIdx = 4;
  p1.bias = b1vt; p1.out8 = A4; p1.ldOut = R_;
  gemm_i8<1><<<dim3((TOK/128)*(R_/128)), 256, 0, stream>>>(p1);

  // fc1_U: [25088,384] x [3072,384]^T -> q5 -> GELU -> q6 (fused as int8 LUT)
  GemmParams p2 = {};
  p2.A = A4; p2.W = W1U; p2.K = R_; p2.MT = TOK/128; p2.NT = H_/128;
  p2.actS = actS; p2.amax = amax; p2.amaxIdx = 5; p2.sInIdx = 4; p2.sOutIdx = 5; p2.sOut2Idx = 6;
  p2.bias = b1u; p2.out8 = A6; p2.ldOut = H_; p2.lutG = LUTG;
  gemm_i8<2><<<dim3((TOK/128)*(H_/128)), 256, 0, stream>>>(p2);

  // fc2_VT: [25088,3072] x [384,3072]^T -> q7
  GemmParams p3 = {};
  p3.A = A6; p3.W = W2VT; p3.K = H_; p3.MT = TOK/128; p3.NT = R_/128;
  p3.actS = actS; p3.amax = amax; p3.amaxIdx = 6; p3.sInIdx = 6; p3.sOutIdx = 7;
  p3.bias = b2vt; p3.out8 = A7; p3.ldOut = R_;
  gemm_i8<1><<<dim3((TOK/128)*(R_/128)), 256, 0, stream>>>(p3);

  // fc2_U: [25088,384] x [768,384]^T -> q3 -> gamma2 -> +x1 -> q9 -> out fp32
  GemmParams p4 = {};
  p4.A = A7; p4.W = W2U; p4.K = R_; p4.MT = TOK/128; p4.NT = D_/128;
  p4.actS = actS; p4.amax = amax; p4.amaxIdx = 7; p4.sInIdx = 7;
  p4.bias = b2u; p4.g2s9 = qvec + 3840; p4.X1qIn = X1Q; p4.outF = out; p4.ldOut = D_;
  gemm_i8<3><<<dim3((TOK/128)*(D_/128)), 256, 0, stream>>>(p4);
}